// Round 1
// baseline (10753.460 us; speedup 1.0000x reference)
//
#include <hip/hip_runtime.h>
#include <math.h>

#define HH 1024
#define WW 1024
#define NBATCH 32
#define TILE 64
#define PLANE (HH*WW)
#define NELEM (NBATCH*PLANE)
#define LSTR 72   // LDS row stride (floats)

__device__ __forceinline__ float fmin3(float a, float b, float c){ return fminf(fminf(a,b),c); }
__device__ __forceinline__ float fmax3(float a, float b, float c){ return fmaxf(fmaxf(a,b),c); }

// skel = relu(img - dilate3x3(erode_cross(img))); halo 2
__global__ __launch_bounds__(256) void skel_init_kernel(const float* __restrict__ img,
                                                        float* __restrict__ skel) {
    __shared__ float sA[68*LSTR];   // img region 68x68 (OOB = +inf)
    __shared__ float sB[66*LSTR];   // E region 66x66 (OOB = -inf, feeds dilate)
    const int n = blockIdx.z;
    const int by = blockIdx.y * TILE, bx = blockIdx.x * TILE;
    const int tid = threadIdx.x;
    const float* im = img + (size_t)n * PLANE;

    const int gy0 = by - 2, gx0 = bx - 2;
    for (int i = tid; i < 68*68; i += 256) {
        int r = i / 68, c = i - r*68;
        int gy = gy0 + r, gx = gx0 + c;
        float v = INFINITY;
        if (gy >= 0 && gy < HH && gx >= 0 && gx < WW) v = im[gy*WW + gx];
        sA[r*LSTR + c] = v;
    }
    __syncthreads();
    // E at local (r,c) <-> global (by-1+r, bx-1+c) = sA(r+1,c+1)
    for (int i = tid; i < 66*66; i += 256) {
        int r = i / 66, c = i - r*66;
        int gy = by - 1 + r, gx = bx - 1 + c;
        float v = -INFINITY;
        if (gy >= 0 && gy < HH && gx >= 0 && gx < WW) {
            const float* p = &sA[(r+1)*LSTR + (c+1)];
            v = fminf(fmin3(p[-LSTR], p[0], p[LSTR]), fminf(p[-1], p[1]));
        }
        sB[r*LSTR + c] = v;
    }
    __syncthreads();
    float* sk = skel + (size_t)n * PLANE;
    int ox = tid & 63;
    for (int oy = tid >> 6; oy < TILE; oy += 4) {
        const float* p = &sB[oy*LSTR + ox];
        float d = fmax3(fmax3(p[0],        p[1],        p[2]),
                        fmax3(p[LSTR],     p[LSTR+1],   p[LSTR+2]),
                        fmax3(p[2*LSTR],   p[2*LSTR+1], p[2*LSTR+2]));
        float center = sA[(oy+2)*LSTR + (ox+2)];
        int g = (by+oy)*WW + (bx+ox);
        sk[g] = fmaxf(center - d, 0.0f);
    }
}

// One soft_skel loop iteration, fused:
//   E = erode(src); delta = relu(E - dilate(erode(E)));
//   skel += relu(delta - skel*delta); dst = E.        halo 3
__global__ __launch_bounds__(256) void skel_iter_kernel(const float* __restrict__ src,
                                                        float* __restrict__ dst,
                                                        float* __restrict__ skel) {
    __shared__ float sA[70*LSTR];   // img 70x70, later overwritten with E2 66x66
    __shared__ float sB[68*LSTR];   // E 68x68
    const int n = blockIdx.z;
    const int by = blockIdx.y * TILE, bx = blockIdx.x * TILE;
    const int tid = threadIdx.x;
    const float* im = src + (size_t)n * PLANE;

    const int gy0 = by - 3, gx0 = bx - 3;
    for (int i = tid; i < 70*70; i += 256) {
        int r = i / 70, c = i - r*70;
        int gy = gy0 + r, gx = gx0 + c;
        float v = INFINITY;
        if (gy >= 0 && gy < HH && gx >= 0 && gx < WW) v = im[gy*WW + gx];
        sA[r*LSTR + c] = v;
    }
    __syncthreads();
    // E local (r,c) <-> global (by-2+r, bx-2+c) = sA(r+1,c+1); OOB -> +inf (erode pad)
    for (int i = tid; i < 68*68; i += 256) {
        int r = i / 68, c = i - r*68;
        int gy = by - 2 + r, gx = bx - 2 + c;
        float v = INFINITY;
        if (gy >= 0 && gy < HH && gx >= 0 && gx < WW) {
            const float* p = &sA[(r+1)*LSTR + (c+1)];
            v = fminf(fmin3(p[-LSTR], p[0], p[LSTR]), fminf(p[-1], p[1]));
        }
        sB[r*LSTR + c] = v;
    }
    __syncthreads();
    // E2 local (r,c) <-> global (by-1+r, bx-1+c) = sB(r+1,c+1); OOB -> -inf (dilate pad)
    for (int i = tid; i < 66*66; i += 256) {
        int r = i / 66, c = i - r*66;
        int gy = by - 1 + r, gx = bx - 1 + c;
        float v = -INFINITY;
        if (gy >= 0 && gy < HH && gx >= 0 && gx < WW) {
            const float* p = &sB[(r+1)*LSTR + (c+1)];
            v = fminf(fmin3(p[-LSTR], p[0], p[LSTR]), fminf(p[-1], p[1]));
        }
        sA[r*LSTR + c] = v;
    }
    __syncthreads();
    float* sk = skel + (size_t)n * PLANE;
    float* dd = dst  + (size_t)n * PLANE;
    int ox = tid & 63;
    for (int oy = tid >> 6; oy < TILE; oy += 4) {
        const float* p = &sA[oy*LSTR + ox];
        float d = fmax3(fmax3(p[0],        p[1],        p[2]),
                        fmax3(p[LSTR],     p[LSTR+1],   p[LSTR+2]),
                        fmax3(p[2*LSTR],   p[2*LSTR+1], p[2*LSTR+2]));
        float e = sB[(oy+2)*LSTR + (ox+2)];
        int g = (by+oy)*WW + (bx+ox);
        float delta = fmaxf(e - d, 0.0f);
        float s = sk[g];
        sk[g] = s + fmaxf(delta - s*delta, 0.0f);
        dd[g] = e;
    }
}

// acc[0] += sum(skel*w); acc[1] += sum(skel)
__global__ __launch_bounds__(256) void reduce_kernel(const float* __restrict__ skel,
                                                     const float* __restrict__ w,
                                                     double* __restrict__ acc) {
    double s0 = 0.0, s1 = 0.0;
    int stride = gridDim.x * blockDim.x;
    for (int i = blockIdx.x * blockDim.x + threadIdx.x; i < NELEM/4; i += stride) {
        float4 a = ((const float4*)skel)[i];
        float4 b = ((const float4*)w)[i];
        s0 += (double)(a.x*b.x) + (double)(a.y*b.y) + (double)(a.z*b.z) + (double)(a.w*b.w);
        s1 += (double)a.x + (double)a.y + (double)a.z + (double)a.w;
    }
    #pragma unroll
    for (int off = 32; off > 0; off >>= 1) {
        s0 += __shfl_down(s0, off, 64);
        s1 += __shfl_down(s1, off, 64);
    }
    __shared__ double ws0[4], ws1[4];
    int lane = threadIdx.x & 63, wid = threadIdx.x >> 6;
    if (lane == 0) { ws0[wid] = s0; ws1[wid] = s1; }
    __syncthreads();
    if (threadIdx.x == 0) {
        atomicAdd(&acc[0], ws0[0]+ws0[1]+ws0[2]+ws0[3]);
        atomicAdd(&acc[1], ws1[0]+ws1[1]+ws1[2]+ws1[3]);
    }
}

__global__ void final_kernel(const double* __restrict__ acc, float* __restrict__ out) {
    double tprec = (acc[0] + 1e-5) / (acc[1] + 1e-5);
    double tsens = (acc[2] + 1e-5) / (acc[3] + 1e-5);
    out[0] = (float)(1.0 - 2.0 * (tprec * tsens) / (tprec + tsens));
}

extern "C" void kernel_launch(void* const* d_in, const int* in_sizes, int n_in,
                              void* d_out, int out_size, void* d_ws, size_t ws_size,
                              hipStream_t stream) {
    const float* target = (const float*)d_in[0];
    const float* inputs = (const float*)d_in[1];
    float* out = (float*)d_out;
    char* ws = (char*)d_ws;
    double* acc = (double*)ws;                       // 4 doubles
    const size_t S = (size_t)NELEM * sizeof(float);  // 128 MiB
    float* imgA = (float*)(ws + 256);
    float* imgB = (float*)(ws + 256 + S);
    float* skel = (float*)(ws + 256 + 2*S);

    hipMemsetAsync(acc, 0, 4*sizeof(double), stream);

    dim3 grid(WW/TILE, HH/TILE, NBATCH);
    dim3 block(256);

    // k=0: skel_pred = soft_skel(inputs), weight = target -> acc[0..1]
    // k=1: skel_true = soft_skel(target), weight = inputs -> acc[2..3]
    const float* srcs[2] = {inputs, target};
    const float* wts[2]  = {target, inputs};
    for (int k = 0; k < 2; k++) {
        skel_init_kernel<<<grid, block, 0, stream>>>(srcs[k], skel);
        const float* cur = srcs[k];
        for (int j = 0; j < 25; j++) {
            float* dstb = (j & 1) ? imgB : imgA;
            skel_iter_kernel<<<grid, block, 0, stream>>>(cur, dstb, skel);
            cur = dstb;
        }
        reduce_kernel<<<dim3(2048), block, 0, stream>>>(skel, wts[k], acc + 2*k);
    }
    final_kernel<<<1, 1, 0, stream>>>(acc, out);
}

// Round 2
// 4112.486 us; speedup vs baseline: 2.6148x; 2.6148x over previous
//
#include <hip/hip_runtime.h>
#include <math.h>

#define HH 1024
#define WW 1024
#define NB 32
#define PLANE (HH*WW)
#define RROWS 118      // region rows: gy in [by-27, by+90]
#define RSTR  120      // region cols: gx in [bx-28, bx+91], multiple of 4
#define NGRP  (RROWS*30)   // 3540 float4 groups

__device__ __forceinline__ float nanf_() { return __int_as_float(0x7fc00000); }

// Full soft_skel fused: 26-step erode chain in LDS (in-place, register-staged),
// dilate+delta+skel update in VGPRs, fused masked reduction.
__global__ __launch_bounds__(256) void cldice_fused(const float* __restrict__ inputs,
                                                    const float* __restrict__ target,
                                                    double* __restrict__ acc) {
    __shared__ float buf[RROWS*RSTR];   // 56,640 B
    const int tid = threadIdx.x;
    const int bx = blockIdx.x * 64, by = blockIdx.y * 64;
    const int img = blockIdx.z >> 5, n = blockIdx.z & 31;
    const float* xsrc = (img == 0) ? inputs : target;   // skel of this
    const float* wsrc = (img == 0) ? target : inputs;   // weighted by this
    const float* im = xsrc + (size_t)n * PLANE;

    // region fully inside image? (gx in [bx-28, bx+91], gy in [by-27, by+90])
    const bool interior = (bx >= 64 && bx <= 896 && by >= 64 && by <= 896);

    // ---- initial load: region -> LDS, NaN outside image ----
    #pragma unroll
    for (int g = 0; g < 14; g++) {
        int gi = tid + g*256;
        if (gi < NGRP) {
            int row = gi / 30, c0 = (gi - row*30)*4;
            int gy = by - 27 + row, gx = bx - 28 + c0;
            float4 v;
            if (interior) {
                v = *(const float4*)&im[(size_t)gy*WW + gx];
            } else {
                bool oky = ((unsigned)gy < (unsigned)HH);
                v.x = (oky && (unsigned)(gx+0) < (unsigned)WW) ? im[(size_t)gy*WW + gx+0] : nanf_();
                v.y = (oky && (unsigned)(gx+1) < (unsigned)WW) ? im[(size_t)gy*WW + gx+1] : nanf_();
                v.z = (oky && (unsigned)(gx+2) < (unsigned)WW) ? im[(size_t)gy*WW + gx+2] : nanf_();
                v.w = (oky && (unsigned)(gx+3) < (unsigned)WW) ? im[(size_t)gy*WW + gx+3] : nanf_();
            }
            *(float4*)&buf[row*RSTR + c0] = v;
        }
    }
    __syncthreads();

    float4 skel[4];
    float4 xsave[4];

    for (int t = 0; t < 26; t++) {
        // ---- Phase A: erode x_t -> staged regs (5-point cross min); save x_t tile ----
        float4 st[14];
        #pragma unroll
        for (int g = 0; g < 14; g++) {
            int gi = tid + g*256;
            int row = gi / 30, c0 = (gi - row*30)*4;
            bool act = (gi < NGRP) & (row >= t+1) & (row <= 116 - t);
            if (act) {
                const float* p = &buf[row*RSTR + c0];
                float4 up = *(const float4*)(p - RSTR);
                float4 md = *(const float4*)(p);
                float4 dn = *(const float4*)(p + RSTR);
                float lf = p[-1], rt = p[4];
                // erode = min over {up, down, center, left, right}
                float4 e;
                e.x = fminf(fminf(up.x, dn.x), fminf(md.x, fminf(lf,   md.y)));
                e.y = fminf(fminf(up.y, dn.y), fminf(md.y, fminf(md.x, md.z)));
                e.z = fminf(fminf(up.z, dn.z), fminf(md.z, fminf(md.y, md.w)));
                e.w = fminf(fminf(up.w, dn.w), fminf(md.w, fminf(md.z, rt)));
                if (!interior) {
                    // re-mark out-of-image pixels as NaN (pad for both min & max)
                    int gy = by - 27 + row, gx = bx - 28 + c0;
                    bool oky = ((unsigned)gy < (unsigned)HH);
                    if (!(oky && (unsigned)(gx+0) < (unsigned)WW)) e.x = nanf_();
                    if (!(oky && (unsigned)(gx+1) < (unsigned)WW)) e.y = nanf_();
                    if (!(oky && (unsigned)(gx+2) < (unsigned)WW)) e.z = nanf_();
                    if (!(oky && (unsigned)(gx+3) < (unsigned)WW)) e.w = nanf_();
                }
                st[g] = e;
            }
        }
        #pragma unroll
        for (int j = 0; j < 4; j++) {   // save x_t at this thread's tile pixels
            int gi = tid + j*256;
            int row = 27 + (gi >> 4), col = 28 + (gi & 15)*4;
            xsave[j] = *(const float4*)&buf[row*RSTR + col];
        }
        __syncthreads();
        // ---- Phase B: write x_{t+1} back in place ----
        #pragma unroll
        for (int g = 0; g < 14; g++) {
            int gi = tid + g*256;
            int row = gi / 30, c0 = (gi - row*30)*4;
            if ((gi < NGRP) & (row >= t+1) & (row <= 116 - t))
                *(float4*)&buf[row*RSTR + c0] = st[g];
        }
        __syncthreads();
        // ---- Phase C: d = dilate3x3(x_{t+1}) at tile; delta_t; skel update ----
        #pragma unroll
        for (int j = 0; j < 4; j++) {
            int gi = tid + j*256;
            int row = 27 + (gi >> 4), col = 28 + (gi & 15)*4;
            const float* p = &buf[row*RSTR + col];
            float4 up = *(const float4*)(p - RSTR);
            float4 md = *(const float4*)(p);
            float4 dn = *(const float4*)(p + RSTR);
            float l0 = p[-RSTR-1], l1 = p[-1], l2 = p[RSTR-1];
            float r0 = p[-RSTR+4], r1 = p[4], r2 = p[RSTR+4];
            float4 cm;
            cm.x = fmaxf(fmaxf(up.x, md.x), dn.x);
            cm.y = fmaxf(fmaxf(up.y, md.y), dn.y);
            cm.z = fmaxf(fmaxf(up.z, md.z), dn.z);
            cm.w = fmaxf(fmaxf(up.w, md.w), dn.w);
            float lm = fmaxf(fmaxf(l0, l1), l2);
            float rm = fmaxf(fmaxf(r0, r1), r2);
            float4 d;
            d.x = fmaxf(lm,   fmaxf(cm.x, cm.y));
            d.y = fmaxf(cm.x, fmaxf(cm.y, cm.z));
            d.z = fmaxf(cm.y, fmaxf(cm.z, cm.w));
            d.w = fmaxf(cm.z, fmaxf(cm.w, rm));
            float4 dl;
            dl.x = fmaxf(xsave[j].x - d.x, 0.0f);
            dl.y = fmaxf(xsave[j].y - d.y, 0.0f);
            dl.z = fmaxf(xsave[j].z - d.z, 0.0f);
            dl.w = fmaxf(xsave[j].w - d.w, 0.0f);
            if (t == 0) {
                skel[j] = dl;
            } else {
                skel[j].x += fmaxf(dl.x - skel[j].x*dl.x, 0.0f);
                skel[j].y += fmaxf(dl.y - skel[j].y*dl.y, 0.0f);
                skel[j].z += fmaxf(dl.z - skel[j].z*dl.z, 0.0f);
                skel[j].w += fmaxf(dl.w - skel[j].w*dl.w, 0.0f);
            }
        }
        // no barrier needed here: next Phase A only reads what C read; next
        // writes (Phase B) are behind the Phase A->B barrier.
    }

    // ---- fused reduction: s0 = sum(skel*w), s1 = sum(skel) ----
    double s0 = 0.0, s1 = 0.0;
    const float* wim = wsrc + (size_t)n * PLANE;
    #pragma unroll
    for (int j = 0; j < 4; j++) {
        int gi = tid + j*256;
        int ty = gi >> 4, tx = (gi & 15)*4;
        float4 wv = *(const float4*)&wim[(size_t)(by+ty)*WW + (bx+tx)];
        s0 += (double)(skel[j].x*wv.x) + (double)(skel[j].y*wv.y)
            + (double)(skel[j].z*wv.z) + (double)(skel[j].w*wv.w);
        s1 += (double)skel[j].x + (double)skel[j].y + (double)skel[j].z + (double)skel[j].w;
    }
    #pragma unroll
    for (int off = 32; off > 0; off >>= 1) {
        s0 += __shfl_down(s0, off, 64);
        s1 += __shfl_down(s1, off, 64);
    }
    __syncthreads();                 // buf no longer needed; reuse for block reduce
    double* sh = (double*)buf;
    int lane = tid & 63, wv_ = tid >> 6;
    if (lane == 0) { sh[wv_] = s0; sh[4 + wv_] = s1; }
    __syncthreads();
    if (tid == 0) {
        atomicAdd(&acc[img*2 + 0], sh[0]+sh[1]+sh[2]+sh[3]);
        atomicAdd(&acc[img*2 + 1], sh[4]+sh[5]+sh[6]+sh[7]);
    }
}

__global__ void final_kernel(const double* __restrict__ acc, float* __restrict__ out) {
    double tprec = (acc[0] + 1e-5) / (acc[1] + 1e-5);
    double tsens = (acc[2] + 1e-5) / (acc[3] + 1e-5);
    out[0] = (float)(1.0 - 2.0 * (tprec * tsens) / (tprec + tsens));
}

extern "C" void kernel_launch(void* const* d_in, const int* in_sizes, int n_in,
                              void* d_out, int out_size, void* d_ws, size_t ws_size,
                              hipStream_t stream) {
    const float* target = (const float*)d_in[0];
    const float* inputs = (const float*)d_in[1];
    float* out = (float*)d_out;
    double* acc = (double*)d_ws;   // 4 doubles

    hipMemsetAsync(acc, 0, 4*sizeof(double), stream);

    dim3 grid(WW/64, HH/64, NB*2);   // z: img*32 + n
    cldice_fused<<<grid, dim3(256), 0, stream>>>(inputs, target, acc);
    final_kernel<<<1, 1, 0, stream>>>(acc, out);
}

// Round 4
// 1241.432 us; speedup vs baseline: 8.6621x; 3.3127x over previous
//
#include <hip/hip_runtime.h>
#include <hip/hip_fp16.h>

#define HH 1024
#define WW 1024
#define NB 32
#define PLANE (HH*WW)
#define RR 118         // region rows: gy in [by-27, by+90]
#define RC 128         // region cols (halves) = row stride; gx in [bx-32, bx+95]
typedef unsigned int u32;
typedef unsigned short u16;

// packed half2 ops via ISA asm: v_pk_min/max_f16 return the non-NaN operand (IEEE),
// so NaN doubles as +inf pad (erode) AND -inf pad (dilate).
static __device__ __forceinline__ u32 pmin(u32 a, u32 b){ u32 d; asm("v_pk_min_f16 %0,%1,%2":"=v"(d):"v"(a),"v"(b)); return d; }
static __device__ __forceinline__ u32 pmax(u32 a, u32 b){ u32 d; asm("v_pk_max_f16 %0,%1,%2":"=v"(d):"v"(a),"v"(b)); return d; }
static __device__ __forceinline__ u32 padd(u32 a, u32 b){ u32 d; asm("v_pk_add_f16 %0,%1,%2":"=v"(d):"v"(a),"v"(b)); return d; }
static __device__ __forceinline__ u32 pmul(u32 a, u32 b){ u32 d; asm("v_pk_mul_f16 %0,%1,%2":"=v"(d):"v"(a),"v"(b)); return d; }
static __device__ __forceinline__ u32 psub(u32 a, u32 b){ u32 d; asm("v_pk_add_f16 %0,%1,%2 neg_lo:[0,1] neg_hi:[0,1]":"=v"(d):"v"(a),"v"(b)); return d; }
static __device__ __forceinline__ float h2f(u32 s){ float f; asm("v_cvt_f32_f16 %0,%1":"=v"(f):"v"(s)); return f; }
static __device__ __forceinline__ u32 cvt2(float a, float b){
    typedef __fp16 h2v __attribute__((ext_vector_type(2)));   // exact builtin return type
    union { h2v h; u32 u; } r; r.h = __builtin_amdgcn_cvt_pkrtz(a,b); return r.u;
}
// DPP: lane i <- lane i-1 (row_shr:1) / lane i+1 (row_shl:1) within 16-lane rows.
// 16-lane row boundaries coincide with region cols 0/127 (never needed).
#define DPP_SHR1(x) ((u32)__builtin_amdgcn_mov_dpp((int)(x), 0x111, 0xf, 0xf, true))
#define DPP_SHL1(x) ((u32)__builtin_amdgcn_mov_dpp((int)(x), 0x101, 0xf, 0xf, true))
#define QNAN2 0x7e007e00u
#define AB(hi,lo) (((lo)>>16)|((hi)<<16))

__global__ __launch_bounds__(256,4) void cldice_fused(const float* __restrict__ inputs,
                                                      const float* __restrict__ target,
                                                      double* __restrict__ acc) {
    __shared__ __align__(16) u16 buf[RR*RC];   // 30208 B
    const int tid = threadIdx.x;
    const int bx = blockIdx.x*64, by = blockIdx.y*64;
    const int img = blockIdx.z >> 5, n = blockIdx.z & 31;
    const float* xsrc = (img==0) ? inputs : target;   // skeletonize this
    const float* wsrc = (img==0) ? target : inputs;   // weight for tprec/tsens
    const float* im = xsrc + (size_t)n*PLANE;
    const bool interior = (bx>=64 && bx<=896 && by>=64 && by<=896);
    const int r0 = tid>>4, c = tid&15;       // group row/col; addr = tid*8 + g*2048
    const int gx = bx - 32 + 8*c;            // 8-px groups never straddle image edge
    const bool colok = ((unsigned)gx < (unsigned)WW);

    // ---- initial load: fp32 global -> fp16 LDS; out-of-image groups = NaN ----
    #pragma unroll
    for (int g = 0; g < 8; g++) {
        int r = r0 + g*16;
        if (r < RR) {
            int gy = by - 27 + r;
            uint4 v;
            if (interior || (colok && (unsigned)gy < (unsigned)HH)) {
                const float* p = im + (size_t)gy*WW + gx;
                float4 f0 = *(const float4*)p, f1 = *(const float4*)(p+4);
                v.x = cvt2(f0.x,f0.y); v.y = cvt2(f0.z,f0.w);
                v.z = cvt2(f1.x,f1.y); v.w = cvt2(f1.z,f1.w);
            } else {
                v = make_uint4(QNAN2,QNAN2,QNAN2,QNAN2);
            }
            *(uint4*)&buf[tid*8 + g*2048] = v;
        }
    }
    __syncthreads();

    u32 sk[2][4] = {{0,0,0,0},{0,0,0,0}};   // skel (half2 x4 per 8-px group), s=0 start is exact
    const int bc0 = 3456 + (tid>>3)*128 + (tid&7)*8;          // tile group j=0
    const int bc1 = 3456 + ((tid+256)>>3)*128 + (tid&7)*8;    // tile group j=1

    #pragma unroll 1
    for (int t = 0; t < 26; t++) {
        // ---- Phase A: erode x_t (5-pt cross min) -> st regs; rows [t+1,116-t] ----
        uint4 st[8];
        #pragma unroll
        for (int g = 0; g < 8; g++) {
            int r = r0 + g*16;
            bool act = (r >= t+1) & (r <= 116-t);
            if (act) {
                int base = tid*8 + g*2048;
                uint4 up = *(const uint4*)&buf[base-RC];
                uint4 md = *(const uint4*)&buf[base];
                uint4 dn = *(const uint4*)&buf[base+RC];
                u32 lfs = DPP_SHR1(md.w);     // left px = neighbor group's px7 (high half)
                u32 rts = DPP_SHL1(md.x);     // right px = neighbor group's px0 (low half)
                u32 vx = pmin(up.x,dn.x), vy = pmin(up.y,dn.y);
                u32 vz = pmin(up.z,dn.z), vw = pmin(up.w,dn.w);
                u32 B1 = AB(md.y,md.x), B2 = AB(md.z,md.y), B3 = AB(md.w,md.z);
                u32 B4 = (md.w>>16)|(rts<<16);
                u32 M0 = (md.x<<16)|(lfs>>16);
                uint4 e;
                e.x = pmin(pmin(vx,md.x), pmin(M0,B1));
                e.y = pmin(pmin(vy,md.y), pmin(B1,B2));
                e.z = pmin(pmin(vz,md.z), pmin(B2,B3));
                e.w = pmin(pmin(vw,md.w), pmin(B3,B4));
                if (!interior) {
                    int gy = by - 27 + r;
                    if (!(colok && (unsigned)gy < (unsigned)HH))
                        e = make_uint4(QNAN2,QNAN2,QNAN2,QNAN2);   // keep OOB = NaN
                }
                st[g] = e;
            }
        }
        // save x_t at this thread's tile groups before overwrite
        uint4 xs0 = *(const uint4*)&buf[bc0];
        uint4 xs1 = *(const uint4*)&buf[bc1];
        __syncthreads();
        // ---- Phase B: x_{t+1} -> LDS in place ----
        #pragma unroll
        for (int g = 0; g < 8; g++) {
            int r = r0 + g*16;
            if ((r >= t+1) & (r <= 116-t))
                *(uint4*)&buf[tid*8 + g*2048] = st[g];
        }
        __syncthreads();
        // ---- Phase C: d = dilate3x3(x_{t+1}) at tile; delta; skel update ----
        #pragma unroll
        for (int j = 0; j < 2; j++) {
            int base = j ? bc1 : bc0;
            uint4 xs = j ? xs1 : xs0;
            uint4 up = *(const uint4*)&buf[base-RC];
            uint4 md = *(const uint4*)&buf[base];
            uint4 dn = *(const uint4*)&buf[base+RC];
            uint4 vm;
            vm.x = pmax(pmax(up.x,dn.x),md.x);
            vm.y = pmax(pmax(up.y,dn.y),md.y);
            vm.z = pmax(pmax(up.z,dn.z),md.z);
            vm.w = pmax(pmax(up.w,dn.w),md.w);
            u32 lfm = DPP_SHR1(vm.w);
            u32 rtm = DPP_SHL1(vm.x);
            if ((tid&7)==0) {   // left tile-row boundary: real 3-row vertical max from LDS
                u32 a = buf[base-RC-1], b = buf[base-1], d2 = buf[base+RC-1];
                lfm = pmax(pmax(a,b),d2) << 16;
            }
            if ((tid&7)==7) {   // right boundary
                u32 a = buf[base-RC+8], b = buf[base+8], d2 = buf[base+RC+8];
                rtm = pmax(pmax(a,b),d2) & 0xffffu;
            }
            u32 B1 = AB(vm.y,vm.x), B2 = AB(vm.z,vm.y), B3 = AB(vm.w,vm.z);
            u32 B4 = (vm.w>>16)|(rtm<<16);
            u32 M0 = (vm.x<<16)|(lfm>>16);
            uint4 d;
            d.x = pmax(pmax(M0,B1), vm.x);
            d.y = pmax(pmax(B1,B2), vm.y);
            d.z = pmax(pmax(B2,B3), vm.z);
            d.w = pmax(pmax(B3,B4), vm.w);
            uint4 dl;
            dl.x = pmax(psub(xs.x,d.x), 0u);
            dl.y = pmax(psub(xs.y,d.y), 0u);
            dl.z = pmax(psub(xs.z,d.z), 0u);
            dl.w = pmax(psub(xs.w,d.w), 0u);
            sk[j][0] = padd(sk[j][0], pmax(psub(dl.x, pmul(sk[j][0],dl.x)), 0u));
            sk[j][1] = padd(sk[j][1], pmax(psub(dl.y, pmul(sk[j][1],dl.y)), 0u));
            sk[j][2] = padd(sk[j][2], pmax(psub(dl.z, pmul(sk[j][2],dl.z)), 0u));
            sk[j][3] = padd(sk[j][3], pmax(psub(dl.w, pmul(sk[j][3],dl.w)), 0u));
        }
        // next Phase A only reads; writes are behind the A->B barrier
    }

    // ---- fused reduction: s0 = sum(skel*w), s1 = sum(skel) ----
    double s0 = 0.0, s1 = 0.0;
    const float* wim = wsrc + (size_t)n*PLANE;
    #pragma unroll
    for (int j = 0; j < 2; j++) {
        int ti = tid + j*256, ty = ti>>3, cx = ti&7;
        const float* p = wim + (size_t)(by+ty)*WW + bx + 8*cx;
        float4 w0 = *(const float4*)p, w1 = *(const float4*)(p+4);
        float f0 = h2f(sk[j][0]&0xffffu), f1 = h2f(sk[j][0]>>16);
        float f2 = h2f(sk[j][1]&0xffffu), f3 = h2f(sk[j][1]>>16);
        float f4 = h2f(sk[j][2]&0xffffu), f5 = h2f(sk[j][2]>>16);
        float f6 = h2f(sk[j][3]&0xffffu), f7 = h2f(sk[j][3]>>16);
        s0 += (double)(f0*w0.x) + (double)(f1*w0.y) + (double)(f2*w0.z) + (double)(f3*w0.w)
            + (double)(f4*w1.x) + (double)(f5*w1.y) + (double)(f6*w1.z) + (double)(f7*w1.w);
        s1 += (double)f0 + (double)f1 + (double)f2 + (double)f3
            + (double)f4 + (double)f5 + (double)f6 + (double)f7;
    }
    #pragma unroll
    for (int off = 32; off > 0; off >>= 1) {
        s0 += __shfl_down(s0, off, 64);
        s1 += __shfl_down(s1, off, 64);
    }
    __syncthreads();               // buf dead; reuse for block reduction
    double* sh = (double*)buf;
    int lane = tid & 63, wid = tid >> 6;
    if (lane == 0) { sh[wid] = s0; sh[4+wid] = s1; }
    __syncthreads();
    if (tid == 0) {
        atomicAdd(&acc[img*2 + 0], sh[0]+sh[1]+sh[2]+sh[3]);
        atomicAdd(&acc[img*2 + 1], sh[4]+sh[5]+sh[6]+sh[7]);
    }
}

__global__ void final_kernel(const double* __restrict__ acc, float* __restrict__ out) {
    double tprec = (acc[0] + 1e-5) / (acc[1] + 1e-5);
    double tsens = (acc[2] + 1e-5) / (acc[3] + 1e-5);
    out[0] = (float)(1.0 - 2.0 * (tprec * tsens) / (tprec + tsens));
}

extern "C" void kernel_launch(void* const* d_in, const int* in_sizes, int n_in,
                              void* d_out, int out_size, void* d_ws, size_t ws_size,
                              hipStream_t stream) {
    const float* target = (const float*)d_in[0];
    const float* inputs = (const float*)d_in[1];
    float* out = (float*)d_out;
    double* acc = (double*)d_ws;

    (void)hipMemsetAsync(acc, 0, 4*sizeof(double), stream);
    dim3 grid(WW/64, HH/64, NB*2);
    cldice_fused<<<grid, dim3(256), 0, stream>>>(inputs, target, acc);
    final_kernel<<<1, 1, 0, stream>>>(acc, out);
}